// Round 1
// baseline (2405.055 us; speedup 1.0000x reference)
//
#include <hip/hip_runtime.h>
#include <cstdint>

// Problem constants (KimiDeltaAttention): B=2, S=2048, HID=2048, H=16, D=128, K=4
#define BB 2
#define SS 2048
#define HID_ 2048
#define HH 16
#define DD 128
#define HD 2048      // H*D
#define MM 4096      // B*S

typedef unsigned short u16;
typedef __bf16 bf16x8 __attribute__((ext_vector_type(8)));
typedef float f32x4 __attribute__((ext_vector_type(4)));
typedef unsigned short u16x8 __attribute__((ext_vector_type(8)));

__device__ __forceinline__ u16 f2bf(float f) {
  unsigned int u = __float_as_uint(f);
  u += 0x7FFFu + ((u >> 16) & 1u);   // RNE
  return (u16)(u >> 16);
}

__device__ __forceinline__ float sigmoidf_(float x) { return 1.0f / (1.0f + expf(-x)); }

// ---------------- elementwise f32 -> bf16 ----------------
__global__ void cvt_bf16_kernel(const float* __restrict__ in, u16* __restrict__ out, int n) {
  int i = blockIdx.x * blockDim.x + threadIdx.x;
  if (i < n) out[i] = f2bf(in[i]);
}

// ---------------- transpose + convert: in[K][N] f32 -> out[N][K] bf16 ----------------
__global__ __launch_bounds__(256) void transpose_bf16_kernel(
    const float* __restrict__ in, u16* __restrict__ out, int K, int N) {
  __shared__ float tile[32][33];
  int n0 = blockIdx.x * 32, k0 = blockIdx.y * 32;
  int tx = threadIdx.x, ty = threadIdx.y;
#pragma unroll
  for (int i = 0; i < 32; i += 8)
    tile[ty + i][tx] = in[(size_t)(k0 + ty + i) * N + (n0 + tx)];
  __syncthreads();
#pragma unroll
  for (int i = 0; i < 32; i += 8)
    out[(size_t)(n0 + ty + i) * K + (k0 + tx)] = f2bf(tile[tx][ty + i]);
}

// ---------------- bf16 MFMA GEMM: C[M][N] f32 = A[M][K] @ Bt[N][K]^T ----------------
// 128x128 tile per block, 4 waves in 2x2, each wave 4x4 frags of 16x16x32 MFMA.
__global__ __launch_bounds__(256) void gemm_bf16_kernel(
    const u16* __restrict__ A, const u16* __restrict__ Bt, float* __restrict__ C,
    int M, int N, int K) {
  __shared__ u16 As[128 * 32];
  __shared__ u16 Bs[128 * 32];
  const int tid = threadIdx.x;
  const int tileN = blockIdx.x * 128, tileM = blockIdx.y * 128;
  const int lane = tid & 63, wv = tid >> 6;
  const int wm = (wv & 1) * 64, wn = (wv >> 1) * 64;
  const int frm = lane & 15, fk = (lane >> 4) * 8;   // A[m=lane&15][k=quad*8+j] (verified layout)
  const int srow = tid >> 1, scol = (tid & 1) * 16;
  const u16* Ap = A + (size_t)(tileM + srow) * K + scol;
  const u16* Bp = Bt + (size_t)(tileN + srow) * K + scol;
  f32x4 acc[4][4];
#pragma unroll
  for (int i = 0; i < 4; ++i)
#pragma unroll
    for (int j = 0; j < 4; ++j) acc[i][j] = (f32x4)0.0f;
  for (int k0 = 0; k0 < K; k0 += 32) {
    u16x8 a0 = *(const u16x8*)(Ap + k0);
    u16x8 a1 = *(const u16x8*)(Ap + k0 + 8);
    u16x8 b0 = *(const u16x8*)(Bp + k0);
    u16x8 b1 = *(const u16x8*)(Bp + k0 + 8);
    *(u16x8*)(&As[srow * 32 + scol]) = a0;
    *(u16x8*)(&As[srow * 32 + scol + 8]) = a1;
    *(u16x8*)(&Bs[srow * 32 + scol]) = b0;
    *(u16x8*)(&Bs[srow * 32 + scol + 8]) = b1;
    __syncthreads();
    bf16x8 af[4], bfr[4];
#pragma unroll
    for (int t = 0; t < 4; ++t)
      af[t] = *(const bf16x8*)(&As[(wm + t * 16 + frm) * 32 + fk]);
#pragma unroll
    for (int t = 0; t < 4; ++t)
      bfr[t] = *(const bf16x8*)(&Bs[(wn + t * 16 + frm) * 32 + fk]);
#pragma unroll
    for (int mt = 0; mt < 4; ++mt)
#pragma unroll
      for (int nt = 0; nt < 4; ++nt)
        acc[mt][nt] = __builtin_amdgcn_mfma_f32_16x16x32_bf16(af[mt], bfr[nt], acc[mt][nt], 0, 0, 0);
    __syncthreads();
  }
  // C/D layout: col=lane&15, row=(lane>>4)*4+reg (m89/m91-verified)
  const int crow = (lane >> 4) * 4, ccol = lane & 15;
#pragma unroll
  for (int mt = 0; mt < 4; ++mt)
#pragma unroll
    for (int nt = 0; nt < 4; ++nt) {
      float* cp = C + (size_t)(tileM + wm + mt * 16 + crow) * N + (tileN + wn + nt * 16 + ccol);
#pragma unroll
      for (int i = 0; i < 4; ++i) cp[(size_t)i * N] = acc[mt][nt][i];
    }
}

// ---------------- l2norm over D=128, in-place; one wave per (token,head) ----------------
__global__ __launch_bounds__(256) void l2norm_kernel(float* __restrict__ x) {
  int idx = blockIdx.x * 4 + (threadIdx.x >> 6);
  int lane = threadIdx.x & 63;
  float* p = x + (size_t)idx * DD;
  float2 v = *(float2*)(p + lane * 2);
  float ss = v.x * v.x + v.y * v.y;
#pragma unroll
  for (int o = 32; o > 0; o >>= 1) ss += __shfl_xor(ss, o);
  float r = rsqrtf(ss + 1e-6f);
  v.x *= r; v.y *= r;
  *(float2*)(p + lane * 2) = v;
}

// ---------------- causal depthwise conv (K=4) + SiLU ----------------
__global__ void conv_silu_kernel(const float* __restrict__ x, const float* __restrict__ w,
                                 float* __restrict__ y, int n) {
  int id = blockIdx.x * blockDim.x + threadIdx.x;
  if (id >= n) return;
  int c = id & (HD - 1);
  int s = (id >> 11) & (SS - 1);
  float acc = 0.f;
#pragma unroll
  for (int t = 0; t < 4; ++t) {
    int sp = s - 3 + t;
    if (sp >= 0) acc += w[t * HD + c] * x[id + (t - 3) * HD];
  }
  y[id] = acc * sigmoidf_(acc);
}

// ---------------- beta = sigmoid(hidden @ Wb) ; Wb[HID][16] ----------------
__global__ __launch_bounds__(256) void beta_kernel(const float* __restrict__ hid,
                                                   const float* __restrict__ Wb,
                                                   float* __restrict__ beta) {
  int row = blockIdx.x;                  // 0..MM-1
  int tid = threadIdx.x;
  int h = tid & 15, chunk = tid >> 4;    // 16 chunks of 128
  const float* hp = hid + (size_t)row * HID_;
  float acc = 0.f;
  int d0 = chunk * 128;
  for (int i = 0; i < 128; ++i) acc += hp[d0 + i] * Wb[(size_t)(d0 + i) * 16 + h];
  __shared__ float red[256];
  red[tid] = acc;
  __syncthreads();
  if (tid < 16) {
    float s = 0.f;
#pragma unroll
    for (int j = 0; j < 16; ++j) s += red[j * 16 + tid];
    beta[(size_t)row * 16 + tid] = 1.f / (1.f + expf(-s));
  }
}

// ---------------- g = -exp(A_log[h]) * softplus(glin + dt_bias), in-place ----------------
__global__ void kda_g_kernel(float* __restrict__ glin, const float* __restrict__ A_log,
                             const float* __restrict__ dt_bias, int n) {
  int id = blockIdx.x * blockDim.x + threadIdx.x;
  if (id >= n) return;
  int c = id & (HD - 1);
  int h = c >> 7;
  float x = glin[id] + dt_bias[c];
  float sp = (x > 20.f) ? x : log1pf(expf(x));
  glin[id] = -expf(A_log[h]) * sp;
}

// ---------------- delta-rule scan ----------------
// grid: (b,h,cg) = 2*16*4 blocks; block 256 = 32 cols x 8 rowgroups(16 rows).
// State S[k=128][v=32 cols per block], each thread owns 16 (k) x 1 (v) in regs.
__global__ __launch_bounds__(256) void scan_kernel(
    const float* __restrict__ q, const float* __restrict__ k,
    const float* __restrict__ v, const float* __restrict__ g,
    const float* __restrict__ beta, float* __restrict__ attn) {
  int bid = blockIdx.x;
  int cg = bid & 3, bh = bid >> 2;
  int h = bh & (HH - 1), b = bh >> 4;
  int tid = threadIdx.x;
  int cl = tid & 31, rg = tid >> 5;
  int r0 = rg * 16;
  size_t base = ((size_t)b * SS) * HD + (size_t)h * DD;
  const float* qp = q + base;
  const float* kp = k + base;
  const float* vp = v + base + cg * 32;
  const float* gp = g + base;
  const float* bp = beta + (size_t)b * SS * HH + h;
  float st[16];
#pragma unroll
  for (int i = 0; i < 16; ++i) st[i] = 0.f;
  __shared__ float sk[2][128], sq[2][128], seg[2][128], sv[2][32];
  __shared__ float pred[2][8][32], pout[2][8][32];
  const float scale = 0.08838834764831845f;  // D^-0.5
  for (int s = 0; s < SS; ++s) {
    int p = s & 1;
    if (tid < 128) {
      size_t off = (size_t)s * HD + tid;
      sk[p][tid] = kp[off];
      sq[p][tid] = qp[off] * scale;
      seg[p][tid] = expf(gp[off]);
    } else if (tid < 160) {
      sv[p][tid - 128] = vp[(size_t)s * HD + (tid - 128)];
    }
    float bt = bp[(size_t)s * HH];
    __syncthreads();
    float kr[16];
    float acc = 0.f;
#pragma unroll
    for (int i = 0; i < 16; ++i) {
      kr[i] = sk[p][r0 + i];
      st[i] *= seg[p][r0 + i];
      acc += kr[i] * st[i];
    }
    pred[p][rg][cl] = acc;
    __syncthreads();
    float sum = 0.f;
#pragma unroll
    for (int j = 0; j < 8; ++j) sum += pred[p][j][cl];
    float be = bt * (sv[p][cl] - sum);
    float acco = 0.f;
#pragma unroll
    for (int i = 0; i < 16; ++i) {
      st[i] += kr[i] * be;
      acco += sq[p][r0 + i] * st[i];
    }
    pout[p][rg][cl] = acco;
    __syncthreads();
    if (rg == 0) {
      float so = acco;
#pragma unroll
      for (int j = 1; j < 8; ++j) so += pout[p][j][cl];
      attn[((size_t)b * SS + s) * HD + (size_t)h * DD + cg * 32 + cl] = so;
    }
  }
}

// ---------------- RMSNorm * rms_scale * sigmoid(gate) -> bf16 preout ----------------
__global__ __launch_bounds__(256) void gate_rms_kernel(
    const float* __restrict__ attn, const float* __restrict__ gate,
    const float* __restrict__ rms_scale, u16* __restrict__ preout) {
  int idx = blockIdx.x * 4 + (threadIdx.x >> 6);
  int lane = threadIdx.x & 63;
  const float* ap = attn + (size_t)idx * DD;
  const float* gp = gate + (size_t)idx * DD;
  float2 a = *(const float2*)(ap + lane * 2);
  float ss = a.x * a.x + a.y * a.y;
#pragma unroll
  for (int o = 32; o > 0; o >>= 1) ss += __shfl_xor(ss, o);
  float r = rsqrtf(ss * (1.0f / 128.0f) + 1e-5f);
  float2 gg = *(const float2*)(gp + lane * 2);
  int d = lane * 2;
  float o0 = a.x * r * rms_scale[d] * sigmoidf_(gg.x);
  float o1 = a.y * r * rms_scale[d + 1] * sigmoidf_(gg.y);
  preout[(size_t)idx * DD + d] = f2bf(o0);
  preout[(size_t)idx * DD + d + 1] = f2bf(o1);
}

extern "C" void kernel_launch(void* const* d_in, const int* in_sizes, int n_in,
                              void* d_out, int out_size, void* d_ws, size_t ws_size,
                              hipStream_t stream) {
  const float* hid = (const float*)d_in[0];
  const float* Wq = (const float*)d_in[1];
  const float* Wk = (const float*)d_in[2];
  const float* Wv = (const float*)d_in[3];
  const float* conv_q = (const float*)d_in[4];
  const float* conv_k = (const float*)d_in[5];
  const float* conv_v = (const float*)d_in[6];
  const float* Wb = (const float*)d_in[7];
  const float* Wfa = (const float*)d_in[8];
  const float* Wfb = (const float*)d_in[9];
  const float* Wga = (const float*)d_in[10];
  const float* Wgb = (const float*)d_in[11];
  const float* A_log = (const float*)d_in[12];
  const float* dt_bias = (const float*)d_in[13];
  const float* rms_scale = (const float*)d_in[14];
  const float* Wo = (const float*)d_in[15];
  float* out = (float*)d_out;
  (void)in_sizes; (void)n_in; (void)out_size; (void)ws_size;

  char* w = (char*)d_ws;
  size_t off = 0;
  auto alloc = [&](size_t bytes) -> void* {
    void* p = w + off;
    off += (bytes + 255) & ~(size_t)255;
    return p;
  };
  // total ~184 MiB
  u16* hidb = (u16*)alloc((size_t)MM * HID_ * 2);  // later reused as bf16 preout
  u16* WqT  = (u16*)alloc((size_t)HD * HID_ * 2);
  u16* WkT  = (u16*)alloc((size_t)HD * HID_ * 2);
  u16* WvT  = (u16*)alloc((size_t)HD * HID_ * 2);
  u16* WoT  = (u16*)alloc((size_t)HID_ * HD * 2);
  u16* WfaT = (u16*)alloc((size_t)DD * HID_ * 2);
  u16* WgaT = (u16*)alloc((size_t)DD * HID_ * 2);
  u16* WfbT = (u16*)alloc((size_t)HD * DD * 2);
  u16* WgbT = (u16*)alloc((size_t)HD * DD * 2);
  float* X1 = (float*)alloc((size_t)MM * HD * 4);
  float* X2 = (float*)alloc((size_t)MM * HD * 4);
  float* X3 = (float*)alloc((size_t)MM * HD * 4);
  float* T  = (float*)alloc((size_t)MM * HD * 4);
  float* beta = (float*)alloc((size_t)MM * HH * 4);
  float* fa = (float*)alloc((size_t)MM * DD * 4);
  float* ga = (float*)alloc((size_t)MM * DD * 4);
  u16* fab = (u16*)alloc((size_t)MM * DD * 2);
  u16* gab = (u16*)alloc((size_t)MM * DD * 2);

  dim3 tb(32, 8);
  const int n_full = MM * HD;

  // 1. convert + transpose weights
  cvt_bf16_kernel<<<(n_full + 255) / 256, 256, 0, stream>>>(hid, hidb, n_full);
  transpose_bf16_kernel<<<dim3(HD / 32, HID_ / 32), tb, 0, stream>>>(Wq, WqT, HID_, HD);
  transpose_bf16_kernel<<<dim3(HD / 32, HID_ / 32), tb, 0, stream>>>(Wk, WkT, HID_, HD);
  transpose_bf16_kernel<<<dim3(HD / 32, HID_ / 32), tb, 0, stream>>>(Wv, WvT, HID_, HD);
  transpose_bf16_kernel<<<dim3(HID_ / 32, HD / 32), tb, 0, stream>>>(Wo, WoT, HD, HID_);
  transpose_bf16_kernel<<<dim3(DD / 32, HID_ / 32), tb, 0, stream>>>(Wfa, WfaT, HID_, DD);
  transpose_bf16_kernel<<<dim3(DD / 32, HID_ / 32), tb, 0, stream>>>(Wga, WgaT, HID_, DD);
  transpose_bf16_kernel<<<dim3(HD / 32, DD / 32), tb, 0, stream>>>(Wfb, WfbT, DD, HD);
  transpose_bf16_kernel<<<dim3(HD / 32, DD / 32), tb, 0, stream>>>(Wgb, WgbT, DD, HD);

  // 2. projections
  gemm_bf16_kernel<<<dim3(HD / 128, MM / 128), 256, 0, stream>>>(hidb, WqT, X1, MM, HD, HID_);
  gemm_bf16_kernel<<<dim3(HD / 128, MM / 128), 256, 0, stream>>>(hidb, WkT, X2, MM, HD, HID_);
  gemm_bf16_kernel<<<dim3(HD / 128, MM / 128), 256, 0, stream>>>(hidb, WvT, X3, MM, HD, HID_);
  gemm_bf16_kernel<<<dim3(DD / 128, MM / 128), 256, 0, stream>>>(hidb, WfaT, fa, MM, DD, HID_);
  gemm_bf16_kernel<<<dim3(DD / 128, MM / 128), 256, 0, stream>>>(hidb, WgaT, ga, MM, DD, HID_);
  beta_kernel<<<MM, 256, 0, stream>>>(hid, Wb, beta);

  // 3. l2norm q,k (in place)
  l2norm_kernel<<<MM * HH / 4, 256, 0, stream>>>(X1);
  l2norm_kernel<<<MM * HH / 4, 256, 0, stream>>>(X2);

  // 4. causal conv + silu:  qc=T <- X1, kc=X1 <- X2, vc=X2 <- X3  (X3 then free)
  conv_silu_kernel<<<(n_full + 255) / 256, 256, 0, stream>>>(X1, conv_q, T, n_full);
  conv_silu_kernel<<<(n_full + 255) / 256, 256, 0, stream>>>(X2, conv_k, X1, n_full);
  conv_silu_kernel<<<(n_full + 255) / 256, 256, 0, stream>>>(X3, conv_v, X2, n_full);

  // 5. forget gate: glin = fa@Wfb -> X3, then KDA transform in place
  cvt_bf16_kernel<<<(MM * DD + 255) / 256, 256, 0, stream>>>(fa, fab, MM * DD);
  gemm_bf16_kernel<<<dim3(HD / 128, MM / 128), 256, 0, stream>>>(fab, WfbT, X3, MM, HD, DD);
  kda_g_kernel<<<(n_full + 255) / 256, 256, 0, stream>>>(X3, A_log, dt_bias, n_full);

  // 6. delta-rule scan -> attn (uses d_out as f32 scratch)
  scan_kernel<<<BB * HH * 4, 256, 0, stream>>>(T, X1, X2, X3, beta, out);

  // 7. output gate: gate = ga@Wgb -> T (qc no longer needed)
  cvt_bf16_kernel<<<(MM * DD + 255) / 256, 256, 0, stream>>>(ga, gab, MM * DD);
  gemm_bf16_kernel<<<dim3(HD / 128, MM / 128), 256, 0, stream>>>(gab, WgbT, T, MM, HD, DD);

  // 8. RMSNorm + sigmoid gate -> bf16 preout (reuses hidb)
  gate_rms_kernel<<<MM * HH / 4, 256, 0, stream>>>(out, T, rms_scale, hidb);

  // 9. final projection -> d_out
  gemm_bf16_kernel<<<dim3(HID_ / 128, MM / 128), 256, 0, stream>>>(hidb, WoT, out, MM, HID_, HD);
}

// Round 2
// 1489.280 us; speedup vs baseline: 1.6149x; 1.6149x over previous
//
#include <hip/hip_runtime.h>
#include <cstdint>

// Problem constants: B=2, S=2048, HID=2048, H=16, D=128, K=4
#define BB 2
#define SS 2048
#define HID_ 2048
#define HH 16
#define DD 128
#define HD 2048
#define MM 4096
#define CC 64        // chunk length
#define NCH 32       // chunks per sequence
#define NU 1024      // units = 32 (b*h) * 32 chunks

typedef unsigned short u16;
typedef __bf16 bf16x8 __attribute__((ext_vector_type(8)));
typedef float f32x4 __attribute__((ext_vector_type(4)));
typedef unsigned short u16x8 __attribute__((ext_vector_type(8)));

__device__ __forceinline__ u16 f2bf(float f) {
  unsigned u = __float_as_uint(f);
  u += 0x7FFFu + ((u >> 16) & 1u);   // RNE
  return (u16)(u >> 16);
}
__device__ __forceinline__ float blo(unsigned u) { return __uint_as_float(u << 16); }
__device__ __forceinline__ float bhi(unsigned u) { return __uint_as_float(u & 0xffff0000u); }
__device__ __forceinline__ float sigmoidf_(float x) { return 1.0f / (1.0f + __expf(-x)); }

__device__ __forceinline__ void gll16(const void* g, void* l) {
  __builtin_amdgcn_global_load_lds((const __attribute__((address_space(1))) void*)g,
                                   (__attribute__((address_space(3))) void*)l, 16, 0, 0);
}

// ---------------- elementwise f32 -> bf16 ----------------
__global__ void cvt_bf16_kernel(const float* __restrict__ in, u16* __restrict__ out, int n) {
  int i = blockIdx.x * blockDim.x + threadIdx.x;
  if (i < n) out[i] = f2bf(in[i]);
}

// ---------------- transpose + convert: in[K][N] f32 -> out[N][K] bf16 ----------------
__global__ __launch_bounds__(256) void transpose_bf16_kernel(
    const float* __restrict__ in, u16* __restrict__ out, int K, int N) {
  __shared__ float tile[32][33];
  int n0 = blockIdx.x * 32, k0 = blockIdx.y * 32;
  int tx = threadIdx.x, ty = threadIdx.y;
#pragma unroll
  for (int i = 0; i < 32; i += 8)
    tile[ty + i][tx] = in[(size_t)(k0 + ty + i) * N + (n0 + tx)];
  __syncthreads();
#pragma unroll
  for (int i = 0; i < 32; i += 8)
    out[(size_t)(n0 + ty + i) * K + (k0 + tx)] = f2bf(tile[tx][ty + i]);
}

// ---------------- bf16 MFMA GEMM: C[M][N] f32 = A[M][K] @ Bt[N][K]^T ----------------
// 128x128 tile, 4 waves 2x2, 4x4 frags of 16x16x32; global_load_lds width-16 staging.
__global__ __launch_bounds__(256) void gemm_bf16_kernel(
    const u16* __restrict__ A, const u16* __restrict__ Bt, float* __restrict__ C,
    int M, int N, int K) {
  __shared__ u16 As[128 * 32];
  __shared__ u16 Bs[128 * 32];
  const int tid = threadIdx.x;
  const int tileN = blockIdx.x * 128, tileM = blockIdx.y * 128;
  const int lane = tid & 63, wv = tid >> 6;
  const int wm = (wv & 1) * 64, wn = (wv >> 1) * 64;
  const int frm = lane & 15, fk = (lane >> 4) * 8;
  // staging: wave wv owns rows [32wv,32wv+32); lane i -> row 32wv+16r+(i>>2), 16B piece (i&3)
  const int srow0 = 32 * wv + (lane >> 2);
  const int scol8 = (lane & 3) * 8;
  const u16* Ab0 = A + (size_t)(tileM + srow0) * K + scol8;
  const u16* Ab1 = A + (size_t)(tileM + srow0 + 16) * K + scol8;
  const u16* Bb0 = Bt + (size_t)(tileN + srow0) * K + scol8;
  const u16* Bb1 = Bt + (size_t)(tileN + srow0 + 16) * K + scol8;
  u16* AsL0 = &As[1024 * wv];
  u16* AsL1 = &As[1024 * wv + 512];
  u16* BsL0 = &Bs[1024 * wv];
  u16* BsL1 = &Bs[1024 * wv + 512];
  f32x4 acc[4][4];
#pragma unroll
  for (int i = 0; i < 4; ++i)
#pragma unroll
    for (int j = 0; j < 4; ++j) acc[i][j] = (f32x4)0.0f;
  for (int k0 = 0; k0 < K; k0 += 32) {
    gll16(Ab0 + k0, AsL0);
    gll16(Ab1 + k0, AsL1);
    gll16(Bb0 + k0, BsL0);
    gll16(Bb1 + k0, BsL1);
    __syncthreads();
    bf16x8 af[4], bfr[4];
#pragma unroll
    for (int t = 0; t < 4; ++t)
      af[t] = *(const bf16x8*)(&As[(wm + t * 16 + frm) * 32 + fk]);
#pragma unroll
    for (int t = 0; t < 4; ++t)
      bfr[t] = *(const bf16x8*)(&Bs[(wn + t * 16 + frm) * 32 + fk]);
#pragma unroll
    for (int mt = 0; mt < 4; ++mt)
#pragma unroll
      for (int nt = 0; nt < 4; ++nt)
        acc[mt][nt] = __builtin_amdgcn_mfma_f32_16x16x32_bf16(af[mt], bfr[nt], acc[mt][nt], 0, 0, 0);
    __syncthreads();
  }
  const int crow = (lane >> 4) * 4, ccol = lane & 15;
#pragma unroll
  for (int mt = 0; mt < 4; ++mt)
#pragma unroll
    for (int nt = 0; nt < 4; ++nt) {
      float* cp = C + (size_t)(tileM + wm + mt * 16 + crow) * N + (tileN + wn + nt * 16 + ccol);
#pragma unroll
      for (int i = 0; i < 4; ++i) cp[(size_t)i * N] = acc[mt][nt][i];
    }
}

// ---------------- l2norm over D=128, in-place ----------------
__global__ __launch_bounds__(256) void l2norm_kernel(float* __restrict__ x) {
  int idx = blockIdx.x * 4 + (threadIdx.x >> 6);
  int lane = threadIdx.x & 63;
  float* p = x + (size_t)idx * DD;
  float2 v = *(float2*)(p + lane * 2);
  float ss = v.x * v.x + v.y * v.y;
#pragma unroll
  for (int o = 32; o > 0; o >>= 1) ss += __shfl_xor(ss, o);
  float r = rsqrtf(ss + 1e-6f);
  v.x *= r; v.y *= r;
  *(float2*)(p + lane * 2) = v;
}

// ---------------- causal depthwise conv (K=4) + SiLU ----------------
__global__ void conv_silu_kernel(const float* __restrict__ x, const float* __restrict__ w,
                                 float* __restrict__ y, int n) {
  int id = blockIdx.x * blockDim.x + threadIdx.x;
  if (id >= n) return;
  int c = id & (HD - 1);
  int s = (id >> 11) & (SS - 1);
  float acc = 0.f;
#pragma unroll
  for (int t = 0; t < 4; ++t) {
    int sp = s - 3 + t;
    if (sp >= 0) acc += w[t * HD + c] * x[id + (t - 3) * HD];
  }
  y[id] = acc * sigmoidf_(acc);
}

// ---------------- beta = sigmoid(hidden @ Wb) ----------------
__global__ __launch_bounds__(256) void beta_kernel(const float* __restrict__ hid,
                                                   const float* __restrict__ Wb,
                                                   float* __restrict__ beta) {
  int row = blockIdx.x;
  int tid = threadIdx.x;
  int h = tid & 15, chunk = tid >> 4;
  const float* hp = hid + (size_t)row * HID_;
  float acc = 0.f;
  int d0 = chunk * 128;
  for (int i = 0; i < 128; ++i) acc += hp[d0 + i] * Wb[(size_t)(d0 + i) * 16 + h];
  __shared__ float red[256];
  red[tid] = acc;
  __syncthreads();
  if (tid < 16) {
    float s = 0.f;
#pragma unroll
    for (int j = 0; j < 16; ++j) s += red[j * 16 + tid];
    beta[(size_t)row * 16 + tid] = 1.f / (1.f + __expf(-s));
  }
}

// ---------------- g = -exp(A_log[h]) * softplus(glin + dt_bias), in-place ----------------
__global__ void kda_g_kernel(float* __restrict__ glin, const float* __restrict__ A_log,
                             const float* __restrict__ dt_bias, int n) {
  int id = blockIdx.x * blockDim.x + threadIdx.x;
  if (id >= n) return;
  int c = id & (HD - 1);
  int h = c >> 7;
  float x = glin[id] + dt_bias[c];
  float sp = (x > 20.f) ? x : log1pf(__expf(x));
  glin[id] = -__expf(A_log[h]) * sp;
}

// ---------------- chunk_prep: per (bh,chunk) WY-form quantities ----------------
// In:  q(T),k(X1),v(X2) conv'd, g(X3), beta. Out (in-place / dead buffers):
//   Q~ = q*scale*e^gc  -> bf16-in-f32-slot, strided in T
//   X~ = k*e^(gcL-gc)  -> bf16-in-f32-slot, strided in X1
//   Uv = (I+bA)^-1 bV  -> f32 in-place strided in X2
//   P  = (I+bA)^-1 bW  -> bf16 dense [unit][64*128] (hidb)
//   G^T (t-permuted)   -> bf16 dense [unit][64*64]  (WqT)
//   dlast = e^gcL      -> f32 dense [unit][128]     (fa)
__global__ __launch_bounds__(256) void chunk_prep(
    float* __restrict__ q, float* __restrict__ k, float* __restrict__ v,
    const float* __restrict__ g, const float* __restrict__ beta,
    u16* __restrict__ P, u16* __restrict__ Gt, float* __restrict__ dl) {
  __shared__ float gcl[CC * DD];   // 32 kB
  __shared__ u16 kb[CC * DD];      // 16 kB (bf16 copy of k-chunk)
  __shared__ u16 Ml[CC * CC];      // 8 kB  (M = beta*A, bf16)
  __shared__ float betal[CC];
  const int tid = threadIdx.x;
  const int chunk = blockIdx.x & 31, bh = blockIdx.x >> 5;
  const int h = bh & 15, b = bh >> 4;
  const size_t unit = (size_t)bh * NCH + chunk;
  const size_t base = ((size_t)b * SS + (size_t)chunk * CC) * HD + (size_t)h * DD;
  const float scale = 0.08838834764831845f;

  // phase 1: stage k->LDS bf16; beta; cumsum g -> gcl
  {
    int t = tid >> 2, seg = tid & 3;
    const float* kr = k + base + (size_t)t * HD + seg * 32;
    float kv[32];
#pragma unroll
    for (int i = 0; i < 8; ++i) *(f32x4*)&kv[4 * i] = *(const f32x4*)(kr + 4 * i);
    unsigned pu[16];
#pragma unroll
    for (int i = 0; i < 16; ++i)
      pu[i] = (unsigned)f2bf(kv[2 * i]) | ((unsigned)f2bf(kv[2 * i + 1]) << 16);
    uint4* dst = (uint4*)&kb[t * DD + seg * 32];
#pragma unroll
    for (int i = 0; i < 4; ++i) dst[i] = make_uint4(pu[4 * i], pu[4 * i + 1], pu[4 * i + 2], pu[4 * i + 3]);
  }
  if (tid < CC) betal[tid] = beta[((size_t)b * SS + (size_t)chunk * CC + tid) * HH + h];
  if (tid < DD) {
    int c = tid;
    float acc = 0.f;
    for (int t = 0; t < CC; ++t) {
      acc += g[base + (size_t)t * HD + c];
      gcl[t * DD + c] = acc;
    }
  }
  __syncthreads();

  // phase 2: A -> Ml (bf16, *beta), G -> Gt global (bf16, t-permuted)
  {
    const int t = tid >> 2, cg = tid & 3, c0 = cg * 32;
    float kt[32], qt[32], gct[32];
#pragma unroll
    for (int i = 0; i < 8; ++i) {
      uint2 kk = ((const uint2*)&kb[t * DD + c0])[i];
      kt[4 * i + 0] = blo(kk.x); kt[4 * i + 1] = bhi(kk.x);
      kt[4 * i + 2] = blo(kk.y); kt[4 * i + 3] = bhi(kk.y);
      *(f32x4*)&gct[4 * i] = *(const f32x4*)&gcl[t * DD + c0 + 4 * i];
      *(f32x4*)&qt[4 * i] = *(const f32x4*)(q + base + (size_t)t * HD + c0 + 4 * i);
    }
#pragma unroll
    for (int i = 0; i < 32; ++i) qt[i] *= scale;
    const float bt = betal[t];
    const int jmax = ((tid >> 6) << 4) + 15;
    const int tperm = ((t & 15) << 2) | (t >> 4);
    for (int j = 0; j <= jmax; ++j) {
      float accA = 0.f, accG = 0.f;
#pragma unroll
      for (int i = 0; i < 8; ++i) {
        uint2 kk = ((const uint2*)&kb[j * DD + c0])[i];
        f32x4 gj = *(const f32x4*)&gcl[j * DD + c0 + 4 * i];
        float e0 = __expf(gct[4 * i + 0] - gj[0]);
        float e1 = __expf(gct[4 * i + 1] - gj[1]);
        float e2 = __expf(gct[4 * i + 2] - gj[2]);
        float e3 = __expf(gct[4 * i + 3] - gj[3]);
        float p0 = blo(kk.x) * e0, p1 = bhi(kk.x) * e1;
        float p2 = blo(kk.y) * e2, p3 = bhi(kk.y) * e3;
        accA += kt[4 * i + 0] * p0 + kt[4 * i + 1] * p1 + kt[4 * i + 2] * p2 + kt[4 * i + 3] * p3;
        accG += qt[4 * i + 0] * p0 + qt[4 * i + 1] * p1 + qt[4 * i + 2] * p2 + qt[4 * i + 3] * p3;
      }
      accA += __shfl_xor(accA, 1); accA += __shfl_xor(accA, 2);
      accG += __shfl_xor(accG, 1); accG += __shfl_xor(accG, 2);
      if (cg == 0 && j <= t) {
        Gt[unit * 4096 + j * CC + tperm] = f2bf(accG);
        if (j < t) Ml[t * CC + j] = f2bf(bt * accA);
      }
    }
    if (cg == 0)
      for (int j = t + 1; j < CC; ++j) Gt[unit * 4096 + j * CC + tperm] = 0;
  }
  __syncthreads();

  // phase 3: Q~, X~ (bf16-in-slot, in place), dlast
  {
    const int t = tid >> 2, seg = tid & 3;
    const size_t rb = base + (size_t)t * HD + seg * 32;
    const int e0 = t * DD + seg * 32;
#pragma unroll
    for (int i = 0; i < 32; ++i) {
      int c = seg * 32 + i;
      float gc = gcl[e0 + i];
      float qv = q[rb + i];
      ((unsigned*)q)[rb + i] = (unsigned)f2bf(qv * scale * __expf(gc));
      float kv = __uint_as_float((unsigned)kb[e0 + i] << 16);
      ((unsigned*)k)[rb + i] = (unsigned)f2bf(kv * __expf(gcl[(CC - 1) * DD + c] - gc));
    }
  }
  if (tid < DD) dl[unit * DD + tid] = __expf(gcl[(CC - 1) * DD + tid]);

  // phase 4-5: solve (I+M) X = beta*[V | W], in registers (cols = threads)
  {
    const int col = tid, c = col & 127;
    const bool isV = col < 128;
    float X[CC];
#pragma unroll
    for (int t = 0; t < CC; ++t) {
      float rv;
      if (isV) rv = v[base + (size_t)t * HD + c];
      else rv = __uint_as_float((unsigned)kb[t * DD + c] << 16) * __expf(gcl[t * DD + c]);
      X[t] = betal[t] * rv;
    }
#pragma unroll
    for (int i = 1; i < CC; ++i) {
      float acc = X[i];
#pragma unroll
      for (int jb = 0; jb * 8 < i; ++jb) {
        uint4 mm = *(const uint4*)&Ml[i * CC + jb * 8];
        const int j0 = jb * 8;
        if (j0 + 0 < i) acc -= blo(mm.x) * X[j0 + 0];
        if (j0 + 1 < i) acc -= bhi(mm.x) * X[j0 + 1];
        if (j0 + 2 < i) acc -= blo(mm.y) * X[j0 + 2];
        if (j0 + 3 < i) acc -= bhi(mm.y) * X[j0 + 3];
        if (j0 + 4 < i) acc -= blo(mm.z) * X[j0 + 4];
        if (j0 + 5 < i) acc -= bhi(mm.z) * X[j0 + 5];
        if (j0 + 6 < i) acc -= blo(mm.w) * X[j0 + 6];
        if (j0 + 7 < i) acc -= bhi(mm.w) * X[j0 + 7];
      }
      X[i] = acc;
    }
#pragma unroll
    for (int t = 0; t < CC; ++t) {
      if (isV) v[base + (size_t)t * HD + c] = X[t];
      else P[unit * 8192 + t * DD + c] = f2bf(X[t]);
    }
  }
}

// ---------------- chunk_scan: sequential over 32 chunks; 256 blocks = 32 bh x 8 vgroups ----
__global__ __launch_bounds__(256) void chunk_scan(
    const u16* __restrict__ P, const float* __restrict__ Qg,
    const float* __restrict__ Xg, const u16* __restrict__ Gt,
    const float* __restrict__ Uvg, const float* __restrict__ dl,
    float* __restrict__ attn) {
  __shared__ u16 bufM[CC * 136];    // padded bf16 [64][136]
  __shared__ u16 Gl[CC * CC];       // [j][tperm]
  __shared__ float Sl[16 * 132];    // S^T: [cl][k], padded
  __shared__ float Ul[CC * 17];
  __shared__ float dll[DD];
  const int tid = threadIdx.x, lo = tid & 15, hi = tid >> 4;
  const int vg = blockIdx.x, bh = blockIdx.y;
  const int h = bh & 15, b = bh >> 4;
  for (int i = tid; i < 16 * 132; i += 256) Sl[i] = 0.f;
  __syncthreads();
  for (int s = 0; s < NCH; ++s) {
    const size_t unit = (size_t)bh * NCH + s;
    const size_t base = ((size_t)b * SS + (size_t)s * CC) * HD + (size_t)h * DD;
    // stage P (dense bf16 -> padded LDS), G (gll16), Uv slice, dlast
    {
      int t = tid >> 2, seg = tid & 3;
      const uint4* src = (const uint4*)(P + unit * 8192 + t * DD + seg * 32);
      uint4* dst = (uint4*)&bufM[t * 136 + seg * 32];
#pragma unroll
      for (int i = 0; i < 4; ++i) dst[i] = src[i];
    }
    {
      int wv = tid >> 6, lane = tid & 63;
      gll16(Gt + unit * 4096 + wv * 1024 + lane * 8, &Gl[wv * 1024]);
      gll16(Gt + unit * 4096 + wv * 1024 + 512 + lane * 8, &Gl[wv * 1024 + 512]);
    }
#pragma unroll
    for (int r = 0; r < 4; ++r) {
      int e = r * 256 + tid, t = e >> 4, c = e & 15;
      Ul[t * 17 + c] = Uvg[base + (size_t)t * HD + vg * 16 + c];
    }
    if (tid < DD) dll[tid] = dl[unit * DD + tid];
    __syncthreads();
    // ph1: U[t][lo] -= sum_k P[t][k]*S[k][lo]
    {
      float acc[4] = {0.f, 0.f, 0.f, 0.f};
#pragma unroll
      for (int kb2 = 0; kb2 < 4; ++kb2) {
        float sr[32];
#pragma unroll
        for (int i2 = 0; i2 < 8; ++i2)
          *(f32x4*)&sr[4 * i2] = *(const f32x4*)&Sl[lo * 132 + kb2 * 32 + 4 * i2];
#pragma unroll
        for (int r = 0; r < 4; ++r) {
          const uint4* pp = (const uint4*)&bufM[(r * 16 + hi) * 136 + kb2 * 32];
#pragma unroll
          for (int qq = 0; qq < 4; ++qq) {
            uint4 m = pp[qq];
            int kk = qq * 8;
            acc[r] += blo(m.x) * sr[kk + 0] + bhi(m.x) * sr[kk + 1]
                    + blo(m.y) * sr[kk + 2] + bhi(m.y) * sr[kk + 3]
                    + blo(m.z) * sr[kk + 4] + bhi(m.z) * sr[kk + 5]
                    + blo(m.w) * sr[kk + 6] + bhi(m.w) * sr[kk + 7];
          }
        }
      }
#pragma unroll
      for (int r = 0; r < 4; ++r) Ul[(r * 16 + hi) * 17 + lo] -= acc[r];
    }
    __syncthreads();
    // restage Q~ -> bufM
    {
      int t = tid >> 2, seg = tid & 3;
      const unsigned* qr = (const unsigned*)Qg + base + (size_t)t * HD + seg * 32;
      unsigned uu[32];
#pragma unroll
      for (int i = 0; i < 8; ++i) *(uint4*)&uu[4 * i] = *(const uint4*)(qr + 4 * i);
      unsigned pk[16];
#pragma unroll
      for (int i = 0; i < 16; ++i) pk[i] = (uu[2 * i] & 0xffffu) | (uu[2 * i + 1] << 16);
      uint4* dst = (uint4*)&bufM[t * 136 + seg * 32];
#pragma unroll
      for (int i = 0; i < 4; ++i) dst[i] = make_uint4(pk[4 * i], pk[4 * i + 1], pk[4 * i + 2], pk[4 * i + 3]);
    }
    __syncthreads();
    // ph2: o = Q~ S + G U ; write attn
    {
      float o[4] = {0.f, 0.f, 0.f, 0.f};
#pragma unroll
      for (int kb2 = 0; kb2 < 4; ++kb2) {
        float sr[32];
#pragma unroll
        for (int i2 = 0; i2 < 8; ++i2)
          *(f32x4*)&sr[4 * i2] = *(const f32x4*)&Sl[lo * 132 + kb2 * 32 + 4 * i2];
#pragma unroll
        for (int r = 0; r < 4; ++r) {
          const uint4* pp = (const uint4*)&bufM[(r * 16 + hi) * 136 + kb2 * 32];
#pragma unroll
          for (int qq = 0; qq < 4; ++qq) {
            uint4 m = pp[qq];
            int kk = qq * 8;
            o[r] += blo(m.x) * sr[kk + 0] + bhi(m.x) * sr[kk + 1]
                  + blo(m.y) * sr[kk + 2] + bhi(m.y) * sr[kk + 3]
                  + blo(m.z) * sr[kk + 4] + bhi(m.z) * sr[kk + 5]
                  + blo(m.w) * sr[kk + 6] + bhi(m.w) * sr[kk + 7];
          }
        }
      }
      for (int j = 0; j < CC; ++j) {
        float u = Ul[j * 17 + lo];
        uint2 gg = *(const uint2*)&Gl[j * CC + hi * 4];
        o[0] += blo(gg.x) * u; o[1] += bhi(gg.x) * u;
        o[2] += blo(gg.y) * u; o[3] += bhi(gg.y) * u;
      }
#pragma unroll
      for (int r = 0; r < 4; ++r)
        attn[base + (size_t)(r * 16 + hi) * HD + vg * 16 + lo] = o[r];
    }
    __syncthreads();
    // restage X~ -> bufM
    {
      int t = tid >> 2, seg = tid & 3;
      const unsigned* xr = (const unsigned*)Xg + base + (size_t)t * HD + seg * 32;
      unsigned uu[32];
#pragma unroll
      for (int i = 0; i < 8; ++i) *(uint4*)&uu[4 * i] = *(const uint4*)(xr + 4 * i);
      unsigned pk[16];
#pragma unroll
      for (int i = 0; i < 16; ++i) pk[i] = (uu[2 * i] & 0xffffu) | (uu[2 * i + 1] << 16);
      uint4* dst = (uint4*)&bufM[t * 136 + seg * 32];
#pragma unroll
      for (int i = 0; i < 4; ++i) dst[i] = make_uint4(pk[4 * i], pk[4 * i + 1], pk[4 * i + 2], pk[4 * i + 3]);
    }
    __syncthreads();
    // ph3: S[k][lo] = dlast[k]*S + sum_t X~[t][k]*U[t][lo]
    {
      float sr[8];
#pragma unroll
      for (int i = 0; i < 2; ++i) *(f32x4*)&sr[4 * i] = *(const f32x4*)&Sl[lo * 132 + hi * 8 + 4 * i];
#pragma unroll
      for (int i = 0; i < 8; ++i) sr[i] *= dll[hi * 8 + i];
      for (int t = 0; t < CC; ++t) {
        float u = Ul[t * 17 + lo];
        uint4 m = *(const uint4*)&bufM[t * 136 + hi * 8];
        sr[0] += blo(m.x) * u; sr[1] += bhi(m.x) * u;
        sr[2] += blo(m.y) * u; sr[3] += bhi(m.y) * u;
        sr[4] += blo(m.z) * u; sr[5] += bhi(m.z) * u;
        sr[6] += blo(m.w) * u; sr[7] += bhi(m.w) * u;
      }
#pragma unroll
      for (int i = 0; i < 2; ++i) *(f32x4*)&Sl[lo * 132 + hi * 8 + 4 * i] = *(const f32x4*)&sr[4 * i];
    }
    __syncthreads();
  }
}

// ---------------- RMSNorm * rms_scale * sigmoid(gate) -> bf16 preout ----------------
__global__ __launch_bounds__(256) void gate_rms_kernel(
    const float* __restrict__ attn, const float* __restrict__ gate,
    const float* __restrict__ rms_scale, u16* __restrict__ preout) {
  int idx = blockIdx.x * 4 + (threadIdx.x >> 6);
  int lane = threadIdx.x & 63;
  const float* ap = attn + (size_t)idx * DD;
  const float* gp = gate + (size_t)idx * DD;
  float2 a = *(const float2*)(ap + lane * 2);
  float ss = a.x * a.x + a.y * a.y;
#pragma unroll
  for (int o = 32; o > 0; o >>= 1) ss += __shfl_xor(ss, o);
  float r = rsqrtf(ss * (1.0f / 128.0f) + 1e-5f);
  float2 gg = *(const float2*)(gp + lane * 2);
  int d = lane * 2;
  float o0 = a.x * r * rms_scale[d] * sigmoidf_(gg.x);
  float o1 = a.y * r * rms_scale[d + 1] * sigmoidf_(gg.y);
  preout[(size_t)idx * DD + d] = f2bf(o0);
  preout[(size_t)idx * DD + d + 1] = f2bf(o1);
}

extern "C" void kernel_launch(void* const* d_in, const int* in_sizes, int n_in,
                              void* d_out, int out_size, void* d_ws, size_t ws_size,
                              hipStream_t stream) {
  const float* hid = (const float*)d_in[0];
  const float* Wq = (const float*)d_in[1];
  const float* Wk = (const float*)d_in[2];
  const float* Wv = (const float*)d_in[3];
  const float* conv_q = (const float*)d_in[4];
  const float* conv_k = (const float*)d_in[5];
  const float* conv_v = (const float*)d_in[6];
  const float* Wb = (const float*)d_in[7];
  const float* Wfa = (const float*)d_in[8];
  const float* Wfb = (const float*)d_in[9];
  const float* Wga = (const float*)d_in[10];
  const float* Wgb = (const float*)d_in[11];
  const float* A_log = (const float*)d_in[12];
  const float* dt_bias = (const float*)d_in[13];
  const float* rms_scale = (const float*)d_in[14];
  const float* Wo = (const float*)d_in[15];
  float* out = (float*)d_out;
  (void)in_sizes; (void)n_in; (void)out_size; (void)ws_size;

  char* w = (char*)d_ws;
  size_t off = 0;
  auto alloc = [&](size_t bytes) -> void* {
    void* p = w + off;
    off += (bytes + 255) & ~(size_t)255;
    return p;
  };
  u16* hidb = (u16*)alloc((size_t)MM * HID_ * 2);   // also: P (dense), then preout
  u16* WqT  = (u16*)alloc((size_t)HD * HID_ * 2);   // also: G^T (dense)
  u16* WkT  = (u16*)alloc((size_t)HD * HID_ * 2);
  u16* WvT  = (u16*)alloc((size_t)HD * HID_ * 2);
  u16* WoT  = (u16*)alloc((size_t)HID_ * HD * 2);
  u16* WfaT = (u16*)alloc((size_t)DD * HID_ * 2);
  u16* WgaT = (u16*)alloc((size_t)DD * HID_ * 2);
  u16* WfbT = (u16*)alloc((size_t)HD * DD * 2);
  u16* WgbT = (u16*)alloc((size_t)HD * DD * 2);
  float* X1 = (float*)alloc((size_t)MM * HD * 4);   // kproj -> kc -> X~ (in place)
  float* X2 = (float*)alloc((size_t)MM * HD * 4);   // vproj -> vc -> Uv (in place)
  float* X3 = (float*)alloc((size_t)MM * HD * 4);   // g
  float* T  = (float*)alloc((size_t)MM * HD * 4);   // qc -> Q~ (in place) -> gate
  float* beta = (float*)alloc((size_t)MM * HH * 4);
  float* fa = (float*)alloc((size_t)MM * DD * 4);   // also: dlast (dense)
  float* ga = (float*)alloc((size_t)MM * DD * 4);
  u16* fab = (u16*)alloc((size_t)MM * DD * 2);
  u16* gab = (u16*)alloc((size_t)MM * DD * 2);

  dim3 tb(32, 8);
  const int n_full = MM * HD;

  // 1. convert + transpose weights
  cvt_bf16_kernel<<<(n_full + 255) / 256, 256, 0, stream>>>(hid, hidb, n_full);
  transpose_bf16_kernel<<<dim3(HD / 32, HID_ / 32), tb, 0, stream>>>(Wq, WqT, HID_, HD);
  transpose_bf16_kernel<<<dim3(HD / 32, HID_ / 32), tb, 0, stream>>>(Wk, WkT, HID_, HD);
  transpose_bf16_kernel<<<dim3(HD / 32, HID_ / 32), tb, 0, stream>>>(Wv, WvT, HID_, HD);
  transpose_bf16_kernel<<<dim3(HID_ / 32, HD / 32), tb, 0, stream>>>(Wo, WoT, HD, HID_);
  transpose_bf16_kernel<<<dim3(DD / 32, HID_ / 32), tb, 0, stream>>>(Wfa, WfaT, HID_, DD);
  transpose_bf16_kernel<<<dim3(DD / 32, HID_ / 32), tb, 0, stream>>>(Wga, WgaT, HID_, DD);
  transpose_bf16_kernel<<<dim3(HD / 32, DD / 32), tb, 0, stream>>>(Wfb, WfbT, DD, HD);
  transpose_bf16_kernel<<<dim3(HD / 32, DD / 32), tb, 0, stream>>>(Wgb, WgbT, DD, HD);

  // 2. projections
  gemm_bf16_kernel<<<dim3(HD / 128, MM / 128), 256, 0, stream>>>(hidb, WqT, X1, MM, HD, HID_);
  gemm_bf16_kernel<<<dim3(HD / 128, MM / 128), 256, 0, stream>>>(hidb, WkT, X2, MM, HD, HID_);
  gemm_bf16_kernel<<<dim3(HD / 128, MM / 128), 256, 0, stream>>>(hidb, WvT, X3, MM, HD, HID_);
  gemm_bf16_kernel<<<dim3(DD / 128, MM / 128), 256, 0, stream>>>(hidb, WfaT, fa, MM, DD, HID_);
  gemm_bf16_kernel<<<dim3(DD / 128, MM / 128), 256, 0, stream>>>(hidb, WgaT, ga, MM, DD, HID_);
  beta_kernel<<<MM, 256, 0, stream>>>(hid, Wb, beta);

  // 3. l2norm q,k (X1=qproj, X2=kproj)
  l2norm_kernel<<<MM * HH / 4, 256, 0, stream>>>(X1);
  l2norm_kernel<<<MM * HH / 4, 256, 0, stream>>>(X2);

  // 4. conv+silu: qc=T<-X1, kc=X1<-X2, vc=X2<-X3 (X3 free)
  conv_silu_kernel<<<(n_full + 255) / 256, 256, 0, stream>>>(X1, conv_q, T, n_full);
  conv_silu_kernel<<<(n_full + 255) / 256, 256, 0, stream>>>(X2, conv_k, X1, n_full);
  conv_silu_kernel<<<(n_full + 255) / 256, 256, 0, stream>>>(X3, conv_v, X2, n_full);

  // 5. forget gate: glin = fa@Wfb -> X3, KDA transform in place
  cvt_bf16_kernel<<<(MM * DD + 255) / 256, 256, 0, stream>>>(fa, fab, MM * DD);
  gemm_bf16_kernel<<<dim3(HD / 128, MM / 128), 256, 0, stream>>>(fab, WfbT, X3, MM, HD, DD);
  kda_g_kernel<<<(n_full + 255) / 256, 256, 0, stream>>>(X3, A_log, dt_bias, n_full);

  // 6. chunked delta rule
  chunk_prep<<<NU, 256, 0, stream>>>(T, X1, X2, X3, beta, hidb, WqT, fa);
  chunk_scan<<<dim3(8, 32), 256, 0, stream>>>(hidb, T, X1, WqT, X2, fa, out);

  // 7. output gate: gate = ga@Wgb -> T
  cvt_bf16_kernel<<<(MM * DD + 255) / 256, 256, 0, stream>>>(ga, gab, MM * DD);
  gemm_bf16_kernel<<<dim3(HD / 128, MM / 128), 256, 0, stream>>>(gab, WgbT, T, MM, HD, DD);

  // 8. RMSNorm + sigmoid gate -> bf16 preout (hidb free: P consumed)
  gate_rms_kernel<<<MM * HH / 4, 256, 0, stream>>>(out, T, rms_scale, hidb);

  // 9. final projection
  gemm_bf16_kernel<<<dim3(HID_ / 128, MM / 128), 256, 0, stream>>>(hidb, WoT, out, MM, HID_, HD);
}

// Round 3
// 1248.222 us; speedup vs baseline: 1.9268x; 1.1931x over previous
//
#include <hip/hip_runtime.h>
#include <cstdint>

// Problem constants: B=2, S=2048, HID=2048, H=16, D=128, K=4
#define BB 2
#define SS 2048
#define HID_ 2048
#define HH 16
#define DD 128
#define HD 2048
#define MM 4096
#define CC 64        // chunk length
#define NCH 32       // chunks per sequence
#define NU 1024      // units = 32 (b*h) * 32 chunks

typedef unsigned short u16;
typedef __bf16 bf16x8 __attribute__((ext_vector_type(8)));
typedef float f32x4 __attribute__((ext_vector_type(4)));
typedef unsigned short u16x8 __attribute__((ext_vector_type(8)));

__device__ __forceinline__ u16 f2bf(float f) {
  unsigned u = __float_as_uint(f);
  u += 0x7FFFu + ((u >> 16) & 1u);   // RNE
  return (u16)(u >> 16);
}
__device__ __forceinline__ float blo(unsigned u) { return __uint_as_float(u << 16); }
__device__ __forceinline__ float bhi(unsigned u) { return __uint_as_float(u & 0xffff0000u); }
__device__ __forceinline__ float sigmoidf_(float x) { return 1.0f / (1.0f + __expf(-x)); }

__device__ __forceinline__ void gll16(const void* g, void* l) {
  __builtin_amdgcn_global_load_lds((const __attribute__((address_space(1))) void*)g,
                                   (__attribute__((address_space(3))) void*)l, 16, 0, 0);
}

// ---------------- elementwise f32 -> bf16 ----------------
__global__ void cvt_bf16_kernel(const float* __restrict__ in, u16* __restrict__ out, int n) {
  int i = blockIdx.x * blockDim.x + threadIdx.x;
  if (i < n) out[i] = f2bf(in[i]);
}

// ---------------- transpose + convert: in[K][N] f32 -> out[N][K] bf16 ----------------
__global__ __launch_bounds__(256) void transpose_bf16_kernel(
    const float* __restrict__ in, u16* __restrict__ out, int K, int N) {
  __shared__ float tile[32][33];
  int n0 = blockIdx.x * 32, k0 = blockIdx.y * 32;
  int tx = threadIdx.x, ty = threadIdx.y;
#pragma unroll
  for (int i = 0; i < 32; i += 8)
    tile[ty + i][tx] = in[(size_t)(k0 + ty + i) * N + (n0 + tx)];
  __syncthreads();
#pragma unroll
  for (int i = 0; i < 32; i += 8)
    out[(size_t)(n0 + ty + i) * K + (k0 + tx)] = f2bf(tile[tx][ty + i]);
}

// ---------------- bf16 MFMA GEMM: C[M][N] f32 = A[M][K] @ Bt[N][K]^T ----------------
__global__ __launch_bounds__(256) void gemm_bf16_kernel(
    const u16* __restrict__ A, const u16* __restrict__ Bt, float* __restrict__ C,
    int M, int N, int K) {
  __shared__ u16 As[128 * 32];
  __shared__ u16 Bs[128 * 32];
  const int tid = threadIdx.x;
  const int tileN = blockIdx.x * 128, tileM = blockIdx.y * 128;
  const int lane = tid & 63, wv = tid >> 6;
  const int wm = (wv & 1) * 64, wn = (wv >> 1) * 64;
  const int frm = lane & 15, fk = (lane >> 4) * 8;
  const int srow0 = 32 * wv + (lane >> 2);
  const int scol8 = (lane & 3) * 8;
  const u16* Ab0 = A + (size_t)(tileM + srow0) * K + scol8;
  const u16* Ab1 = A + (size_t)(tileM + srow0 + 16) * K + scol8;
  const u16* Bb0 = Bt + (size_t)(tileN + srow0) * K + scol8;
  const u16* Bb1 = Bt + (size_t)(tileN + srow0 + 16) * K + scol8;
  u16* AsL0 = &As[1024 * wv];
  u16* AsL1 = &As[1024 * wv + 512];
  u16* BsL0 = &Bs[1024 * wv];
  u16* BsL1 = &Bs[1024 * wv + 512];
  f32x4 acc[4][4];
#pragma unroll
  for (int i = 0; i < 4; ++i)
#pragma unroll
    for (int j = 0; j < 4; ++j) acc[i][j] = (f32x4)0.0f;
  for (int k0 = 0; k0 < K; k0 += 32) {
    gll16(Ab0 + k0, AsL0);
    gll16(Ab1 + k0, AsL1);
    gll16(Bb0 + k0, BsL0);
    gll16(Bb1 + k0, BsL1);
    __syncthreads();
    bf16x8 af[4], bfr[4];
#pragma unroll
    for (int t = 0; t < 4; ++t)
      af[t] = *(const bf16x8*)(&As[(wm + t * 16 + frm) * 32 + fk]);
#pragma unroll
    for (int t = 0; t < 4; ++t)
      bfr[t] = *(const bf16x8*)(&Bs[(wn + t * 16 + frm) * 32 + fk]);
#pragma unroll
    for (int mt = 0; mt < 4; ++mt)
#pragma unroll
      for (int nt = 0; nt < 4; ++nt)
        acc[mt][nt] = __builtin_amdgcn_mfma_f32_16x16x32_bf16(af[mt], bfr[nt], acc[mt][nt], 0, 0, 0);
    __syncthreads();
  }
  const int crow = (lane >> 4) * 4, ccol = lane & 15;
#pragma unroll
  for (int mt = 0; mt < 4; ++mt)
#pragma unroll
    for (int nt = 0; nt < 4; ++nt) {
      float* cp = C + (size_t)(tileM + wm + mt * 16 + crow) * N + (tileN + wn + nt * 16 + ccol);
#pragma unroll
      for (int i = 0; i < 4; ++i) cp[(size_t)i * N] = acc[mt][nt][i];
    }
}

// ---------------- l2norm over D=128, in-place ----------------
__global__ __launch_bounds__(256) void l2norm_kernel(float* __restrict__ x) {
  int idx = blockIdx.x * 4 + (threadIdx.x >> 6);
  int lane = threadIdx.x & 63;
  float* p = x + (size_t)idx * DD;
  float2 v = *(float2*)(p + lane * 2);
  float ss = v.x * v.x + v.y * v.y;
#pragma unroll
  for (int o = 32; o > 0; o >>= 1) ss += __shfl_xor(ss, o);
  float r = rsqrtf(ss + 1e-6f);
  v.x *= r; v.y *= r;
  *(float2*)(p + lane * 2) = v;
}

// ---------------- causal depthwise conv (K=4) + SiLU ----------------
__global__ void conv_silu_kernel(const float* __restrict__ x, const float* __restrict__ w,
                                 float* __restrict__ y, int n) {
  int id = blockIdx.x * blockDim.x + threadIdx.x;
  if (id >= n) return;
  int c = id & (HD - 1);
  int s = (id >> 11) & (SS - 1);
  float acc = 0.f;
#pragma unroll
  for (int t = 0; t < 4; ++t) {
    int sp = s - 3 + t;
    if (sp >= 0) acc += w[t * HD + c] * x[id + (t - 3) * HD];
  }
  y[id] = acc * sigmoidf_(acc);
}

// ---------------- beta = sigmoid(hidden @ Wb) ----------------
__global__ __launch_bounds__(256) void beta_kernel(const float* __restrict__ hid,
                                                   const float* __restrict__ Wb,
                                                   float* __restrict__ beta) {
  int row = blockIdx.x;
  int tid = threadIdx.x;
  int h = tid & 15, chunk = tid >> 4;
  const float* hp = hid + (size_t)row * HID_;
  float acc = 0.f;
  int d0 = chunk * 128;
  for (int i = 0; i < 128; ++i) acc += hp[d0 + i] * Wb[(size_t)(d0 + i) * 16 + h];
  __shared__ float red[256];
  red[tid] = acc;
  __syncthreads();
  if (tid < 16) {
    float s = 0.f;
#pragma unroll
    for (int j = 0; j < 16; ++j) s += red[j * 16 + tid];
    beta[(size_t)row * 16 + tid] = 1.f / (1.f + __expf(-s));
  }
}

// ---------------- g = -exp(A_log[h]) * softplus(glin + dt_bias), in-place ----------------
__global__ void kda_g_kernel(float* __restrict__ glin, const float* __restrict__ A_log,
                             const float* __restrict__ dt_bias, int n) {
  int id = blockIdx.x * blockDim.x + threadIdx.x;
  if (id >= n) return;
  int c = id & (HD - 1);
  int h = c >> 7;
  float x = glin[id] + dt_bias[c];
  float sp = (x > 20.f) ? x : log1pf(__expf(x));
  glin[id] = -__expf(A_log[h]) * sp;
}

// ---------------- chunk_prep: per (bh,chunk) WY-form quantities ----------------
// Outputs:
//   P  = (I+bA)^-1 bW     -> bf16 dense [unit][t*128+k]   (hidb)
//   G  (plain [t][j])     -> bf16 dense [unit][t*64+j]    (WqT)
//   Q~ = q*scale*e^gc     -> bf16 dense [unit][t*128+k]   (Qp = WkT..WvT)
//   X~ = k*e^(gcL-gc)     -> bf16 dense TRANSPOSED [unit][k*64+t]  (Xp)
//   Uv = (I+bA)^-1 bV     -> f32 in-place strided in X2
//   dlast = e^gcL         -> f32 dense [unit][128]        (fa)
__global__ __launch_bounds__(256) void chunk_prep(
    const float* __restrict__ q, const float* __restrict__ k, float* __restrict__ v,
    const float* __restrict__ g, const float* __restrict__ beta,
    u16* __restrict__ P, u16* __restrict__ Gt, float* __restrict__ dl,
    u16* __restrict__ Qp, u16* __restrict__ Xp) {
  __shared__ float gcl[CC * DD];   // 32 kB
  __shared__ u16 kb[CC * DD];      // 16 kB
  __shared__ u16 Ml[CC * CC];      // 8 kB
  __shared__ float betal[CC];
  const int tid = threadIdx.x;
  const int chunk = blockIdx.x & 31, bh = blockIdx.x >> 5;
  const int h = bh & 15, b = bh >> 4;
  const size_t unit = (size_t)bh * NCH + chunk;
  const size_t base = ((size_t)b * SS + (size_t)chunk * CC) * HD + (size_t)h * DD;
  const float scale = 0.08838834764831845f;

  // phase 1: stage k->LDS bf16; beta; cumsum g -> gcl
  {
    int t = tid >> 2, seg = tid & 3;
    const float* kr = k + base + (size_t)t * HD + seg * 32;
    float kv[32];
#pragma unroll
    for (int i = 0; i < 8; ++i) *(f32x4*)&kv[4 * i] = *(const f32x4*)(kr + 4 * i);
    unsigned pu[16];
#pragma unroll
    for (int i = 0; i < 16; ++i)
      pu[i] = (unsigned)f2bf(kv[2 * i]) | ((unsigned)f2bf(kv[2 * i + 1]) << 16);
    uint4* dst = (uint4*)&kb[t * DD + seg * 32];
#pragma unroll
    for (int i = 0; i < 4; ++i) dst[i] = make_uint4(pu[4 * i], pu[4 * i + 1], pu[4 * i + 2], pu[4 * i + 3]);
  }
  if (tid < CC) betal[tid] = beta[((size_t)b * SS + (size_t)chunk * CC + tid) * HH + h];
  if (tid < DD) {
    int c = tid;
    float acc = 0.f;
    for (int t = 0; t < CC; ++t) {
      acc += g[base + (size_t)t * HD + c];
      gcl[t * DD + c] = acc;
    }
  }
  __syncthreads();

  // phase 2: A -> Ml (bf16, *beta), G -> Gt global (bf16, plain [t][j])
  {
    const int t = tid >> 2, cg = tid & 3, c0 = cg * 32;
    float kt[32], qt[32], gct[32];
#pragma unroll
    for (int i = 0; i < 8; ++i) {
      uint2 kk = ((const uint2*)&kb[t * DD + c0])[i];
      kt[4 * i + 0] = blo(kk.x); kt[4 * i + 1] = bhi(kk.x);
      kt[4 * i + 2] = blo(kk.y); kt[4 * i + 3] = bhi(kk.y);
      *(f32x4*)&gct[4 * i] = *(const f32x4*)&gcl[t * DD + c0 + 4 * i];
      *(f32x4*)&qt[4 * i] = *(const f32x4*)(q + base + (size_t)t * HD + c0 + 4 * i);
    }
#pragma unroll
    for (int i = 0; i < 32; ++i) qt[i] *= scale;
    const float bt = betal[t];
    const int jmax = ((tid >> 6) << 4) + 15;
    for (int j = 0; j <= jmax; ++j) {
      float accA = 0.f, accG = 0.f;
#pragma unroll
      for (int i = 0; i < 8; ++i) {
        uint2 kk = ((const uint2*)&kb[j * DD + c0])[i];
        f32x4 gj = *(const f32x4*)&gcl[j * DD + c0 + 4 * i];
        float e0 = __expf(gct[4 * i + 0] - gj[0]);
        float e1 = __expf(gct[4 * i + 1] - gj[1]);
        float e2 = __expf(gct[4 * i + 2] - gj[2]);
        float e3 = __expf(gct[4 * i + 3] - gj[3]);
        float p0 = blo(kk.x) * e0, p1 = bhi(kk.x) * e1;
        float p2 = blo(kk.y) * e2, p3 = bhi(kk.y) * e3;
        accA += kt[4 * i + 0] * p0 + kt[4 * i + 1] * p1 + kt[4 * i + 2] * p2 + kt[4 * i + 3] * p3;
        accG += qt[4 * i + 0] * p0 + qt[4 * i + 1] * p1 + qt[4 * i + 2] * p2 + qt[4 * i + 3] * p3;
      }
      accA += __shfl_xor(accA, 1); accA += __shfl_xor(accA, 2);
      accG += __shfl_xor(accG, 1); accG += __shfl_xor(accG, 2);
      if (cg == 0) {
        if (j <= t) {
          Gt[unit * 4096 + t * 64 + j] = f2bf(accG);
          if (j < t) Ml[t * CC + j] = f2bf(bt * accA);
        } else {
          Gt[unit * 4096 + t * 64 + j] = 0;
        }
      }
    }
    if (cg == 0)
      for (int j = jmax + 1; j < CC; ++j) Gt[unit * 4096 + t * 64 + j] = 0;
  }
  __syncthreads();

  // phase 3a: Q~ packed dense [t][k]
  {
    const int t = tid >> 2, seg = tid & 3;
    const size_t rb = base + (size_t)t * HD + seg * 32;
    const int e0 = t * DD + seg * 32;
    float qv[32];
#pragma unroll
    for (int i = 0; i < 8; ++i) *(f32x4*)&qv[4 * i] = *(const f32x4*)(q + rb + 4 * i);
    unsigned pu[16];
#pragma unroll
    for (int i = 0; i < 16; ++i) {
      float a = qv[2 * i] * scale * __expf(gcl[e0 + 2 * i]);
      float c2 = qv[2 * i + 1] * scale * __expf(gcl[e0 + 2 * i + 1]);
      pu[i] = (unsigned)f2bf(a) | ((unsigned)f2bf(c2) << 16);
    }
    uint4* dst = (uint4*)(Qp + unit * 8192 + t * 128 + seg * 32);
    dst[0] = make_uint4(pu[0], pu[1], pu[2], pu[3]);
    dst[1] = make_uint4(pu[4], pu[5], pu[6], pu[7]);
    ((uint4*)(Qp + unit * 8192 + t * 128 + seg * 32 + 16))[0] = make_uint4(pu[8], pu[9], pu[10], pu[11]);
    ((uint4*)(Qp + unit * 8192 + t * 128 + seg * 32 + 24))[0] = make_uint4(pu[12], pu[13], pu[14], pu[15]);
  }
  // phase 3b: X~ packed dense transposed [k][t]
  {
    const int c = tid >> 1, hf = tid & 1;
    const float glast = gcl[(CC - 1) * DD + c];
    unsigned pu[16];
#pragma unroll
    for (int i = 0; i < 16; ++i) {
      int t0 = hf * 32 + 2 * i;
      float x0 = blo((unsigned)kb[t0 * DD + c]) * __expf(glast - gcl[t0 * DD + c]);
      float x1 = blo((unsigned)kb[(t0 + 1) * DD + c]) * __expf(glast - gcl[(t0 + 1) * DD + c]);
      pu[i] = (unsigned)f2bf(x0) | ((unsigned)f2bf(x1) << 16);
    }
    uint4* dst = (uint4*)(Xp + unit * 8192 + c * 64 + hf * 32);
#pragma unroll
    for (int i = 0; i < 4; ++i)
      dst[i] = make_uint4(pu[4 * i], pu[4 * i + 1], pu[4 * i + 2], pu[4 * i + 3]);
  }
  if (tid < DD) dl[unit * DD + tid] = __expf(gcl[(CC - 1) * DD + tid]);

  // phase 4-5: solve (I+M) X = beta*[V | W]
  {
    const int col = tid, c = col & 127;
    const bool isV = col < 128;
    float X[CC];
#pragma unroll
    for (int t = 0; t < CC; ++t) {
      float rv;
      if (isV) rv = v[base + (size_t)t * HD + c];
      else rv = blo((unsigned)kb[t * DD + c]) * __expf(gcl[t * DD + c]);
      X[t] = betal[t] * rv;
    }
#pragma unroll
    for (int i = 1; i < CC; ++i) {
      float acc = X[i];
#pragma unroll
      for (int jb = 0; jb * 8 < i; ++jb) {
        uint4 mm = *(const uint4*)&Ml[i * CC + jb * 8];
        const int j0 = jb * 8;
        if (j0 + 0 < i) acc -= blo(mm.x) * X[j0 + 0];
        if (j0 + 1 < i) acc -= bhi(mm.x) * X[j0 + 1];
        if (j0 + 2 < i) acc -= blo(mm.y) * X[j0 + 2];
        if (j0 + 3 < i) acc -= bhi(mm.y) * X[j0 + 3];
        if (j0 + 4 < i) acc -= blo(mm.z) * X[j0 + 4];
        if (j0 + 5 < i) acc -= bhi(mm.z) * X[j0 + 5];
        if (j0 + 6 < i) acc -= blo(mm.w) * X[j0 + 6];
        if (j0 + 7 < i) acc -= bhi(mm.w) * X[j0 + 7];
      }
      X[i] = acc;
    }
#pragma unroll
    for (int t = 0; t < CC; ++t) {
      if (isV) v[base + (size_t)t * HD + c] = X[t];
      else P[unit * 8192 + t * DD + c] = f2bf(X[t]);
    }
  }
}

// ---------------- state_pass: sequential S-chain; grid (8 vslices, 32 bh) ----------------
// Per step: U = Uv - P*S ; Sst[c] = S (bf16, [v][k]) ; S = diag(dl)*S + X~^T U
__global__ __launch_bounds__(256) void state_pass(
    const u16* __restrict__ P, const u16* __restrict__ Xp,
    const float* __restrict__ Uvg, const float* __restrict__ dl,
    u16* __restrict__ Sst) {
  __shared__ u16 Pb[64 * 136];    // [t][k] padded
  __shared__ u16 Xb[128 * 72];    // [k][t] padded
  __shared__ float S[128 * 20];   // [k][c] c<16, padded
  __shared__ float U[64 * 20];    // [t][c]
  __shared__ float dll[128];
  const int tid = threadIdx.x;
  const int vs = blockIdx.x, bh = blockIdx.y;
  const int h = bh & 15, b = bh >> 4;
  for (int i = tid; i < 128 * 20; i += 256) S[i] = 0.f;
  __syncthreads();
  for (int c = 0; c < NCH; ++c) {
    const size_t unit = (size_t)bh * NCH + c;
    const size_t base = ((size_t)b * SS + (size_t)c * CC) * HD + (size_t)h * DD + vs * 16;
    // stage P, X~
#pragma unroll
    for (int r = 0; r < 4; ++r) {
      int e = r * 256 + tid;
      int t = e >> 4, kp = (e & 15) * 8;
      *(uint4*)&Pb[t * 136 + kp] = ((const uint4*)(P + unit * 8192))[e];
      int kk = e >> 3, tp = (e & 7) * 8;
      *(uint4*)&Xb[kk * 72 + tp] = ((const uint4*)(Xp + unit * 8192))[e];
    }
    // stage Uv slice
    {
      int t = tid >> 2, cg = tid & 3;
      *(f32x4*)&U[t * 20 + cg * 4] = *(const f32x4*)(Uvg + base + (size_t)t * HD + cg * 4);
    }
    if (tid < 128) dll[tid] = dl[unit * DD + tid];
    // store Sst (state entering chunk c) as bf16 [v][k]
    {
      int v2 = tid >> 4, kq = tid & 15;
      unsigned pu[4];
#pragma unroll
      for (int j = 0; j < 4; ++j) {
        float a = S[(kq * 8 + 2 * j) * 20 + v2];
        float bb = S[(kq * 8 + 2 * j + 1) * 20 + v2];
        pu[j] = (unsigned)f2bf(a) | ((unsigned)f2bf(bb) << 16);
      }
      *(uint4*)(Sst + unit * 16384 + (size_t)(vs * 16 + v2) * 128 + kq * 8) =
          make_uint4(pu[0], pu[1], pu[2], pu[3]);
    }
    __syncthreads();
    // U = Uv - P*S
    {
      const int t = tid >> 2, cg = tid & 3;
      f32x4 u = *(f32x4*)&U[t * 20 + cg * 4];
      f32x4 acc = (f32x4)0.f;
      for (int kk = 0; kk < 128; kk += 4) {
        uint2 pk = *(const uint2*)&Pb[t * 136 + kk];
        f32x4 s0 = *(const f32x4*)&S[(kk + 0) * 20 + cg * 4];
        f32x4 s1 = *(const f32x4*)&S[(kk + 1) * 20 + cg * 4];
        f32x4 s2 = *(const f32x4*)&S[(kk + 2) * 20 + cg * 4];
        f32x4 s3 = *(const f32x4*)&S[(kk + 3) * 20 + cg * 4];
        acc += blo(pk.x) * s0;
        acc += bhi(pk.x) * s1;
        acc += blo(pk.y) * s2;
        acc += bhi(pk.y) * s3;
      }
      u -= acc;
      *(f32x4*)&U[t * 20 + cg * 4] = u;
    }
    __syncthreads();
    // S = diag(dl)*S + X~^T U
    {
      const int kk = tid >> 1, cg2 = tid & 1;
      f32x4 sa = *(f32x4*)&S[kk * 20 + cg2 * 8];
      f32x4 sb = *(f32x4*)&S[kk * 20 + cg2 * 8 + 4];
      float dk = dll[kk];
      sa *= dk; sb *= dk;
      for (int t4 = 0; t4 < 64; t4 += 4) {
        uint2 xv = *(const uint2*)&Xb[kk * 72 + t4];
        float x0 = blo(xv.x), x1 = bhi(xv.x), x2 = blo(xv.y), x3 = bhi(xv.y);
        f32x4 u0a = *(const f32x4*)&U[(t4 + 0) * 20 + cg2 * 8];
        f32x4 u0b = *(const f32x4*)&U[(t4 + 0) * 20 + cg2 * 8 + 4];
        f32x4 u1a = *(const f32x4*)&U[(t4 + 1) * 20 + cg2 * 8];
        f32x4 u1b = *(const f32x4*)&U[(t4 + 1) * 20 + cg2 * 8 + 4];
        f32x4 u2a = *(const f32x4*)&U[(t4 + 2) * 20 + cg2 * 8];
        f32x4 u2b = *(const f32x4*)&U[(t4 + 2) * 20 + cg2 * 8 + 4];
        f32x4 u3a = *(const f32x4*)&U[(t4 + 3) * 20 + cg2 * 8];
        f32x4 u3b = *(const f32x4*)&U[(t4 + 3) * 20 + cg2 * 8 + 4];
        sa += x0 * u0a; sb += x0 * u0b;
        sa += x1 * u1a; sb += x1 * u1b;
        sa += x2 * u2a; sb += x2 * u2b;
        sa += x3 * u3a; sb += x3 * u3b;
      }
      *(f32x4*)&S[kk * 20 + cg2 * 8] = sa;
      *(f32x4*)&S[kk * 20 + cg2 * 8 + 4] = sb;
    }
    __syncthreads();
  }
}

// ---------------- out_pass: o = Q~*S + G*(Uv - P*S), MFMA; grid 1024 ----------------
__global__ __launch_bounds__(256) void out_pass(
    const u16* __restrict__ P, const u16* __restrict__ Qp,
    const u16* __restrict__ G, const u16* __restrict__ Sst,
    const float* __restrict__ Uvg, float* __restrict__ attn) {
  __shared__ u16 Sb[128 * 136];   // [v][k]
  __shared__ u16 Pb[64 * 136];    // [t][k]
  __shared__ u16 Qb[64 * 136];    // [t][k]
  __shared__ u16 Gb[64 * 72];     // [t][j]
  __shared__ u16 Ub[128 * 72];    // U^T [v][t]
  const int tid = threadIdx.x;
  const int unit = blockIdx.x;
  const int bh = unit >> 5, c = unit & 31;
  const int h = bh & 15, b = bh >> 4;
  const size_t base = ((size_t)b * SS + (size_t)c * CC) * HD + (size_t)h * DD;
  // stage
#pragma unroll
  for (int r = 0; r < 8; ++r) {
    int e = r * 256 + tid;
    int v = e >> 4, kp = (e & 15) * 8;
    *(uint4*)&Sb[v * 136 + kp] = ((const uint4*)(Sst + (size_t)unit * 16384))[e];
  }
#pragma unroll
  for (int r = 0; r < 4; ++r) {
    int e = r * 256 + tid;
    int t = e >> 4, kp = (e & 15) * 8;
    *(uint4*)&Pb[t * 136 + kp] = ((const uint4*)(P + (size_t)unit * 8192))[e];
    *(uint4*)&Qb[t * 136 + kp] = ((const uint4*)(Qp + (size_t)unit * 8192))[e];
  }
#pragma unroll
  for (int r = 0; r < 2; ++r) {
    int e = r * 256 + tid;
    int t = e >> 3, jp = (e & 7) * 8;
    *(uint4*)&Gb[t * 72 + jp] = ((const uint4*)(G + (size_t)unit * 4096))[e];
  }
  __syncthreads();
  const int w = tid >> 6, lane = tid & 63;
  const int frm = lane & 15, fk = (lane >> 4) * 8;
  const int crow = (lane >> 4) * 4, ccol = lane & 15;
  bf16x8 Pf[4], Qf[4], Gf[2];
#pragma unroll
  for (int kb2 = 0; kb2 < 4; ++kb2) {
    Pf[kb2] = *(const bf16x8*)&Pb[(w * 16 + frm) * 136 + kb2 * 32 + fk];
    Qf[kb2] = *(const bf16x8*)&Qb[(w * 16 + frm) * 136 + kb2 * 32 + fk];
  }
#pragma unroll
  for (int kb2 = 0; kb2 < 2; ++kb2)
    Gf[kb2] = *(const bf16x8*)&Gb[(w * 16 + frm) * 72 + kb2 * 32 + fk];
  f32x4 aps[8], ao[8];
#pragma unroll
  for (int nt = 0; nt < 8; ++nt) { aps[nt] = (f32x4)0.f; ao[nt] = (f32x4)0.f; }
#pragma unroll
  for (int nt = 0; nt < 8; ++nt)
#pragma unroll
    for (int kb2 = 0; kb2 < 4; ++kb2) {
      bf16x8 sf = *(const bf16x8*)&Sb[(nt * 16 + frm) * 136 + kb2 * 32 + fk];
      aps[nt] = __builtin_amdgcn_mfma_f32_16x16x32_bf16(Pf[kb2], sf, aps[nt], 0, 0, 0);
      ao[nt] = __builtin_amdgcn_mfma_f32_16x16x32_bf16(Qf[kb2], sf, ao[nt], 0, 0, 0);
    }
  // U = Uv - P*S -> Ub transposed bf16
#pragma unroll
  for (int nt = 0; nt < 8; ++nt) {
    float un[4];
#pragma unroll
    for (int i = 0; i < 4; ++i) {
      float uv = Uvg[base + (size_t)(w * 16 + crow + i) * HD + nt * 16 + ccol];
      un[i] = uv - aps[nt][i];
    }
    uint2 pk = make_uint2((unsigned)f2bf(un[0]) | ((unsigned)f2bf(un[1]) << 16),
                          (unsigned)f2bf(un[2]) | ((unsigned)f2bf(un[3]) << 16));
    *(uint2*)&Ub[(nt * 16 + ccol) * 72 + w * 16 + crow] = pk;
  }
  __syncthreads();
#pragma unroll
  for (int nt = 0; nt < 8; ++nt)
#pragma unroll
    for (int kb2 = 0; kb2 < 2; ++kb2) {
      bf16x8 uf = *(const bf16x8*)&Ub[(nt * 16 + frm) * 72 + kb2 * 32 + fk];
      ao[nt] = __builtin_amdgcn_mfma_f32_16x16x32_bf16(Gf[kb2], uf, ao[nt], 0, 0, 0);
    }
#pragma unroll
  for (int nt = 0; nt < 8; ++nt)
#pragma unroll
    for (int i = 0; i < 4; ++i)
      attn[base + (size_t)(w * 16 + crow + i) * HD + nt * 16 + ccol] = ao[nt][i];
}

// ---------------- RMSNorm * rms_scale * sigmoid(gate) -> bf16 preout ----------------
__global__ __launch_bounds__(256) void gate_rms_kernel(
    const float* __restrict__ attn, const float* __restrict__ gate,
    const float* __restrict__ rms_scale, u16* __restrict__ preout) {
  int idx = blockIdx.x * 4 + (threadIdx.x >> 6);
  int lane = threadIdx.x & 63;
  const float* ap = attn + (size_t)idx * DD;
  const float* gp = gate + (size_t)idx * DD;
  float2 a = *(const float2*)(ap + lane * 2);
  float ss = a.x * a.x + a.y * a.y;
#pragma unroll
  for (int o = 32; o > 0; o >>= 1) ss += __shfl_xor(ss, o);
  float r = rsqrtf(ss * (1.0f / 128.0f) + 1e-5f);
  float2 gg = *(const float2*)(gp + lane * 2);
  int d = lane * 2;
  float o0 = a.x * r * rms_scale[d] * sigmoidf_(gg.x);
  float o1 = a.y * r * rms_scale[d + 1] * sigmoidf_(gg.y);
  preout[(size_t)idx * DD + d] = f2bf(o0);
  preout[(size_t)idx * DD + d + 1] = f2bf(o1);
}

extern "C" void kernel_launch(void* const* d_in, const int* in_sizes, int n_in,
                              void* d_out, int out_size, void* d_ws, size_t ws_size,
                              hipStream_t stream) {
  const float* hid = (const float*)d_in[0];
  const float* Wq = (const float*)d_in[1];
  const float* Wk = (const float*)d_in[2];
  const float* Wv = (const float*)d_in[3];
  const float* conv_q = (const float*)d_in[4];
  const float* conv_k = (const float*)d_in[5];
  const float* conv_v = (const float*)d_in[6];
  const float* Wb = (const float*)d_in[7];
  const float* Wfa = (const float*)d_in[8];
  const float* Wfb = (const float*)d_in[9];
  const float* Wga = (const float*)d_in[10];
  const float* Wgb = (const float*)d_in[11];
  const float* A_log = (const float*)d_in[12];
  const float* dt_bias = (const float*)d_in[13];
  const float* rms_scale = (const float*)d_in[14];
  const float* Wo = (const float*)d_in[15];
  float* out = (float*)d_out;
  (void)in_sizes; (void)n_in; (void)out_size; (void)ws_size;

  char* w = (char*)d_ws;
  size_t off = 0;
  auto alloc = [&](size_t bytes) -> void* {
    void* p = w + off;
    off += (bytes + 255) & ~(size_t)255;
    return p;
  };
  u16* hidb = (u16*)alloc((size_t)MM * HID_ * 2);   // -> P (dense), then preout
  u16* WqT  = (u16*)alloc((size_t)HD * HID_ * 2);   // -> G (dense)
  u16* WkT  = (u16*)alloc((size_t)HD * HID_ * 2);   // -> Qp (with WvT, contiguous)
  u16* WvT  = (u16*)alloc((size_t)HD * HID_ * 2);
  u16* WoT  = (u16*)alloc((size_t)HID_ * HD * 2);
  u16* WfaT = (u16*)alloc((size_t)DD * HID_ * 2);
  u16* WgaT = (u16*)alloc((size_t)DD * HID_ * 2);
  u16* WfbT = (u16*)alloc((size_t)HD * DD * 2);
  u16* WgbT = (u16*)alloc((size_t)HD * DD * 2);
  float* X1 = (float*)alloc((size_t)MM * HD * 4);   // kproj -> kc
  float* X2 = (float*)alloc((size_t)MM * HD * 4);   // vproj -> vc -> Uv (in place)
  float* X3 = (float*)alloc((size_t)MM * HD * 4);   // g  -> Sst (bf16, exact fit)
  float* T  = (float*)alloc((size_t)MM * HD * 4);   // qc -> gate
  float* beta = (float*)alloc((size_t)MM * HH * 4);
  float* fa = (float*)alloc((size_t)MM * DD * 4);   // -> dlast
  float* ga = (float*)alloc((size_t)MM * DD * 4);
  u16* fab = (u16*)alloc((size_t)MM * DD * 2);
  u16* gab = (u16*)alloc((size_t)MM * DD * 2);
  u16* Xp  = (u16*)alloc((size_t)NU * 8192 * 2);    // X~ transposed dense
  u16* Qp  = WkT;                                   // alias WkT+WvT (16.78 MB)
  u16* Sst = (u16*)X3;

  dim3 tb(32, 8);
  const int n_full = MM * HD;

  // 1. convert + transpose weights
  cvt_bf16_kernel<<<(n_full + 255) / 256, 256, 0, stream>>>(hid, hidb, n_full);
  transpose_bf16_kernel<<<dim3(HD / 32, HID_ / 32), tb, 0, stream>>>(Wq, WqT, HID_, HD);
  transpose_bf16_kernel<<<dim3(HD / 32, HID_ / 32), tb, 0, stream>>>(Wk, WkT, HID_, HD);
  transpose_bf16_kernel<<<dim3(HD / 32, HID_ / 32), tb, 0, stream>>>(Wv, WvT, HID_, HD);
  transpose_bf16_kernel<<<dim3(HID_ / 32, HD / 32), tb, 0, stream>>>(Wo, WoT, HD, HID_);
  transpose_bf16_kernel<<<dim3(DD / 32, HID_ / 32), tb, 0, stream>>>(Wfa, WfaT, HID_, DD);
  transpose_bf16_kernel<<<dim3(DD / 32, HID_ / 32), tb, 0, stream>>>(Wga, WgaT, HID_, DD);
  transpose_bf16_kernel<<<dim3(HD / 32, DD / 32), tb, 0, stream>>>(Wfb, WfbT, DD, HD);
  transpose_bf16_kernel<<<dim3(HD / 32, DD / 32), tb, 0, stream>>>(Wgb, WgbT, DD, HD);

  // 2. projections
  gemm_bf16_kernel<<<dim3(HD / 128, MM / 128), 256, 0, stream>>>(hidb, WqT, X1, MM, HD, HID_);
  gemm_bf16_kernel<<<dim3(HD / 128, MM / 128), 256, 0, stream>>>(hidb, WkT, X2, MM, HD, HID_);
  gemm_bf16_kernel<<<dim3(HD / 128, MM / 128), 256, 0, stream>>>(hidb, WvT, X3, MM, HD, HID_);
  gemm_bf16_kernel<<<dim3(DD / 128, MM / 128), 256, 0, stream>>>(hidb, WfaT, fa, MM, DD, HID_);
  gemm_bf16_kernel<<<dim3(DD / 128, MM / 128), 256, 0, stream>>>(hidb, WgaT, ga, MM, DD, HID_);
  beta_kernel<<<MM, 256, 0, stream>>>(hid, Wb, beta);

  // 3. l2norm q,k
  l2norm_kernel<<<MM * HH / 4, 256, 0, stream>>>(X1);
  l2norm_kernel<<<MM * HH / 4, 256, 0, stream>>>(X2);

  // 4. conv+silu: qc=T<-X1, kc=X1<-X2, vc=X2<-X3 (X3 free)
  conv_silu_kernel<<<(n_full + 255) / 256, 256, 0, stream>>>(X1, conv_q, T, n_full);
  conv_silu_kernel<<<(n_full + 255) / 256, 256, 0, stream>>>(X2, conv_k, X1, n_full);
  conv_silu_kernel<<<(n_full + 255) / 256, 256, 0, stream>>>(X3, conv_v, X2, n_full);

  // 5. forget gate: glin = fa@Wfb -> X3, KDA transform in place
  cvt_bf16_kernel<<<(MM * DD + 255) / 256, 256, 0, stream>>>(fa, fab, MM * DD);
  gemm_bf16_kernel<<<dim3(HD / 128, MM / 128), 256, 0, stream>>>(fab, WfbT, X3, MM, HD, DD);
  kda_g_kernel<<<(n_full + 255) / 256, 256, 0, stream>>>(X3, A_log, dt_bias, n_full);

  // 6. chunked delta rule: prep (parallel) -> state chain (seq) -> outputs (parallel MFMA)
  chunk_prep<<<NU, 256, 0, stream>>>(T, X1, X2, X3, beta, hidb, WqT, fa, Qp, Xp);
  state_pass<<<dim3(8, 32), 256, 0, stream>>>(hidb, Xp, X2, fa, Sst);
  out_pass<<<NU, 256, 0, stream>>>(hidb, Qp, WqT, Sst, X2, out);

  // 7. output gate: gate = ga@Wgb -> T
  cvt_bf16_kernel<<<(MM * DD + 255) / 256, 256, 0, stream>>>(ga, gab, MM * DD);
  gemm_bf16_kernel<<<dim3(HD / 128, MM / 128), 256, 0, stream>>>(gab, WgbT, T, MM, HD, DD);

  // 8. RMSNorm + sigmoid gate -> bf16 preout
  gate_rms_kernel<<<MM * HH / 4, 256, 0, stream>>>(out, T, rms_scale, hidb);

  // 9. final projection
  gemm_bf16_kernel<<<dim3(HID_ / 128, MM / 128), 256, 0, stream>>>(hidb, WoT, out, MM, HID_, HD);
}